// Round 12
// baseline (87.262 us; speedup 1.0000x reference)
//
#include <hip/hip_runtime.h>
#include <hip/hip_bf16.h>

// GCN layer. N=50000, E=800000, D=128, D_OUT=128, f32 in/out.
// out = concat(mean_agg(feature,src,dst), feature) @ W.T + b
//
// R12: node_agg with 8-lane row groups (uint4 over 128B fp8 row): per-edge
// lane-loads halve (16->8), 8 edges in parallel per wave (was 4), unroll 2.
// Rest = R11 (fp8 gather array, separate kernels, BM=128 MFMA GEMM).

#define D_IN 128
#define NB 391          // buckets = ceil(50000/128)
#define BSHIFT 7
#define EPB 4096        // edges per coarse block
#define CAPMAX 2680     // NB*CAP < 2^20 (packed rstart)

typedef __attribute__((ext_vector_type(8))) short bf16x8;
typedef __attribute__((ext_vector_type(4))) float f32x4;
typedef __attribute__((ext_vector_type(2))) float f32x2;

static __device__ inline unsigned short f2bf(float x) {
    union { float f; unsigned u; } c; c.f = x;
    unsigned u = c.u;
    unsigned r = u + 0x7FFFu + ((u >> 16) & 1u);
    return (unsigned short)(r >> 16);
}

// ---- dispatch 1: convert: feature -> Xf bf16 + Xq fp8; W -> Wbf ----
__global__ __launch_bounds__(256) void convert_kernel(const float* __restrict__ feat,
                                                      const float* __restrict__ W,
                                                      unsigned short* __restrict__ Xf,
                                                      unsigned char* __restrict__ Xq,
                                                      unsigned short* __restrict__ Wbf,
                                                      int M, int blocks_f) {
    int b = blockIdx.x;
    if (b < blocks_f) {
        size_t idx = ((size_t)b * 256 + threadIdx.x) * 8;   // f32 element index
        if (idx >= (size_t)M * 128) return;
        float4 v0 = *reinterpret_cast<const float4*>(feat + idx);
        float4 v1 = *reinterpret_cast<const float4*>(feat + idx + 4);
        uint4 p;
        p.x = (unsigned)f2bf(v0.x) | ((unsigned)f2bf(v0.y) << 16);
        p.y = (unsigned)f2bf(v0.z) | ((unsigned)f2bf(v0.w) << 16);
        p.z = (unsigned)f2bf(v1.x) | ((unsigned)f2bf(v1.y) << 16);
        p.w = (unsigned)f2bf(v1.z) | ((unsigned)f2bf(v1.w) << 16);
        *reinterpret_cast<uint4*>(Xf + idx) = p;
        // fp8 e4m3 pack (HW cvt, RNE)
        int w0 = __builtin_amdgcn_cvt_pk_fp8_f32(v0.x, v0.y, 0, false);
        w0 = __builtin_amdgcn_cvt_pk_fp8_f32(v0.z, v0.w, w0, true);
        int w1 = __builtin_amdgcn_cvt_pk_fp8_f32(v1.x, v1.y, 0, false);
        w1 = __builtin_amdgcn_cvt_pk_fp8_f32(v1.z, v1.w, w1, true);
        *reinterpret_cast<uint2*>(Xq + idx) = make_uint2((unsigned)w0, (unsigned)w1);
    } else {
        int idx = ((b - blocks_f) * 256 + (int)threadIdx.x) * 8;
        if (idx >= 128 * 256) return;
        float4 v0 = *reinterpret_cast<const float4*>(W + idx);
        float4 v1 = *reinterpret_cast<const float4*>(W + idx + 4);
        uint4 p;
        p.x = (unsigned)f2bf(v0.x) | ((unsigned)f2bf(v0.y) << 16);
        p.y = (unsigned)f2bf(v0.z) | ((unsigned)f2bf(v0.w) << 16);
        p.z = (unsigned)f2bf(v1.x) | ((unsigned)f2bf(v1.y) << 16);
        p.w = (unsigned)f2bf(v1.z) | ((unsigned)f2bf(v1.w) << 16);
        *reinterpret_cast<uint4*>(Wbf + idx) = p;
    }
}

// ---- dispatch 2: coarse bucket scatter (LDS counting sort by dst>>7) ----
__global__ __launch_bounds__(256) void coarse_scatter_kernel(
    const int* __restrict__ src, const int* __restrict__ dst,
    int* __restrict__ bcursor, unsigned* __restrict__ bedges,
    int CAP, int nE) {
    __shared__ int hist[NB];
    __shared__ int lofs[NB + 1];
    __shared__ int rnk[NB];
    __shared__ int gbase[NB];
    __shared__ int wsum[4];
    __shared__ unsigned staged[EPB];

    const int tid = threadIdx.x;
    const int e0 = blockIdx.x * EPB;
    for (int i = tid; i < NB; i += 256) { hist[i] = 0; rnk[i] = 0; }
    __syncthreads();

    for (int k = 0; k < EPB; k += 256) {
        int e = e0 + k + tid;
        if (e < nE) atomicAdd(&hist[dst[e] >> BSHIFT], 1);
    }
    __syncthreads();

    {   // exclusive scan of hist -> lofs (2 elems/thread)
        int a = (2 * tid < NB) ? hist[2 * tid] : 0;
        int c = (2 * tid + 1 < NB) ? hist[2 * tid + 1] : 0;
        int ps = a + c;
        int x = ps;
        int lane = tid & 63, wv = tid >> 6;
#pragma unroll
        for (int off = 1; off < 64; off <<= 1) {
            int y = __shfl_up(x, off);
            if (lane >= off) x += y;
        }
        if (lane == 63) wsum[wv] = x;
        __syncthreads();
        if (tid == 0) {
            int s = 0;
#pragma unroll
            for (int w = 0; w < 4; w++) { int v = wsum[w]; wsum[w] = s; s += v; }
        }
        __syncthreads();
        int excl = x - ps + wsum[wv];
        if (2 * tid < NB + 1) lofs[2 * tid] = excl;
        if (2 * tid + 1 < NB + 1) lofs[2 * tid + 1] = excl + a;
    }
    __syncthreads();

    for (int i = tid; i < NB; i += 256)
        if (hist[i] > 0) gbase[i] = i * CAP + atomicAdd(&bcursor[i], hist[i]);

    for (int k = 0; k < EPB; k += 256) {
        int e = e0 + k + tid;
        if (e < nE) {
            int d = dst[e];
            int bk = d >> BSHIFT;
            unsigned ed = ((unsigned)d << 16) | (unsigned)src[e];
            int r = atomicAdd(&rnk[bk], 1);
            staged[lofs[bk] + r] = ed;
        }
    }
    __syncthreads();

    int total = lofs[NB];
    for (int i = tid; i < total; i += 256) {
        unsigned ed = staged[i];
        int bk = (int)(ed >> 23);
        int addr = gbase[bk] + (i - lofs[bk]);
        if (addr < (bk + 1) * CAP) bedges[addr] = ed;   // overflow guard
    }
}

// ---- dispatch 3: per-bucket fine counting sort by dst&127; packed rstart ----
__global__ __launch_bounds__(256) void fine_sort_kernel(
    unsigned* __restrict__ bedges, const int* __restrict__ bcursor,
    unsigned* __restrict__ rstart, int CAP, int N) {
    __shared__ int h[128];
    __shared__ int lofs[129];
    __shared__ int rnk[128];
    __shared__ unsigned staged[CAPMAX + 8];

    const int b = blockIdx.x;
    const int S = b * CAP;
    const int tid = threadIdx.x;
    int cnt = min(bcursor[b], CAP);

    if (tid < 128) { h[tid] = 0; rnk[tid] = 0; }
    __syncthreads();
    for (int i = tid; i < cnt; i += 256) {
        unsigned ed = bedges[S + i];
        atomicAdd(&h[(ed >> 16) & 127], 1);
    }
    __syncthreads();
    if (tid < 64) {
        int a = h[2 * tid], c = h[2 * tid + 1];
        int ps = a + c;
        int x = ps;
#pragma unroll
        for (int off = 1; off < 64; off <<= 1) {
            int y = __shfl_up(x, off);
            if (tid >= off) x += y;
        }
        int excl = x - ps;
        lofs[2 * tid] = excl;
        lofs[2 * tid + 1] = excl + a;
        if (tid == 63) lofs[128] = x;
    }
    __syncthreads();
    for (int i = tid; i < cnt; i += 256) {
        unsigned ed = bedges[S + i];
        int ld = (ed >> 16) & 127;
        int r = atomicAdd(&rnk[ld], 1);
        staged[lofs[ld] + r] = ed;
    }
    __syncthreads();
    for (int i = tid; i < cnt; i += 256) bedges[S + i] = staged[i];
    if (tid < 128) {
        int node = b * 128 + tid;
        if (node < N)
            rstart[node] = (((unsigned)(S + lofs[tid])) << 12) | (unsigned)h[tid];
    }
}

// ---- dispatch 4: per-node mean over fp8 rows; 8-lane groups, 8 edges/wave ----
static __device__ inline void acc16(uint4 v, float* a) {
    f32x2 p;
    p = __builtin_amdgcn_cvt_pk_f32_fp8((int)v.x, false); a[0] += p.x;  a[1] += p.y;
    p = __builtin_amdgcn_cvt_pk_f32_fp8((int)v.x, true);  a[2] += p.x;  a[3] += p.y;
    p = __builtin_amdgcn_cvt_pk_f32_fp8((int)v.y, false); a[4] += p.x;  a[5] += p.y;
    p = __builtin_amdgcn_cvt_pk_f32_fp8((int)v.y, true);  a[6] += p.x;  a[7] += p.y;
    p = __builtin_amdgcn_cvt_pk_f32_fp8((int)v.z, false); a[8] += p.x;  a[9] += p.y;
    p = __builtin_amdgcn_cvt_pk_f32_fp8((int)v.z, true);  a[10] += p.x; a[11] += p.y;
    p = __builtin_amdgcn_cvt_pk_f32_fp8((int)v.w, false); a[12] += p.x; a[13] += p.y;
    p = __builtin_amdgcn_cvt_pk_f32_fp8((int)v.w, true);  a[14] += p.x; a[15] += p.y;
}

__global__ __launch_bounds__(256) void node_agg_kernel(const unsigned char* __restrict__ Xq,
                                                       unsigned short* __restrict__ Xh,
                                                       const unsigned* __restrict__ bedges,
                                                       const unsigned* __restrict__ rstart, int N) {
    int wid = (int)((blockIdx.x * (size_t)blockDim.x + threadIdx.x) >> 6);
    if (wid >= N) return;
    const int lane = threadIdx.x & 63;
    const int g = lane >> 3;          // edge group 0..7
    const int sl = lane & 7;          // 16B chunk within 128B row
    const unsigned pk = rstart[wid];
    const int s = (int)(pk >> 12);
    const int cnt = (int)(pk & 4095u);
    const int e = s + cnt;
    const size_t coff = (size_t)sl * 16;

    float a[16];
#pragma unroll
    for (int i = 0; i < 16; i++) a[i] = 0.0f;

    int j = s + g;
    // unroll 2: 2 edges per group in flight -> 16 chains per wave
    for (; j + 8 < e; j += 16) {
        int u0 = (int)(bedges[j] & 0xFFFFu);
        int u1 = (int)(bedges[j + 8] & 0xFFFFu);
        uint4 va = *reinterpret_cast<const uint4*>(Xq + (size_t)u0 * 128 + coff);
        uint4 vb = *reinterpret_cast<const uint4*>(Xq + (size_t)u1 * 128 + coff);
        acc16(va, a);
        acc16(vb, a);
    }
    if (j < e) {
        int u = (int)(bedges[j] & 0xFFFFu);
        uint4 va = *reinterpret_cast<const uint4*>(Xq + (size_t)u * 128 + coff);
        acc16(va, a);
    }
    // fold the 8 groups: lanes sl, sl+8, ..., sl+56 -> lane sl
#pragma unroll
    for (int i = 0; i < 16; i++) {
        a[i] += __shfl_down(a[i], 32);
        a[i] += __shfl_down(a[i], 16);
        a[i] += __shfl_down(a[i], 8);
    }
    if (lane < 8) {
        float r = 1.0f / fmaxf((float)cnt, 1.0f);
        uint4 p0, p1;
        p0.x = (unsigned)f2bf(a[0] * r)  | ((unsigned)f2bf(a[1] * r) << 16);
        p0.y = (unsigned)f2bf(a[2] * r)  | ((unsigned)f2bf(a[3] * r) << 16);
        p0.z = (unsigned)f2bf(a[4] * r)  | ((unsigned)f2bf(a[5] * r) << 16);
        p0.w = (unsigned)f2bf(a[6] * r)  | ((unsigned)f2bf(a[7] * r) << 16);
        p1.x = (unsigned)f2bf(a[8] * r)  | ((unsigned)f2bf(a[9] * r) << 16);
        p1.y = (unsigned)f2bf(a[10] * r) | ((unsigned)f2bf(a[11] * r) << 16);
        p1.z = (unsigned)f2bf(a[12] * r) | ((unsigned)f2bf(a[13] * r) << 16);
        p1.w = (unsigned)f2bf(a[14] * r) | ((unsigned)f2bf(a[15] * r) << 16);
        char* dstp = (char*)Xh + (size_t)wid * 256 + sl * 32;
        *reinterpret_cast<uint4*>(dstp) = p0;
        *reinterpret_cast<uint4*>(dstp + 16) = p1;
    }
}

// ---- dispatch 5: out[M,128] = [Xh|Xf]bf16 @ Wbf[128,256]^T + b via MFMA ----
__global__ __launch_bounds__(256) void gcn_gemm_kernel(
    const unsigned short* __restrict__ Xh, const unsigned short* __restrict__ Xf,
    const unsigned short* __restrict__ Wbf,
    const float* __restrict__ bias, float* __restrict__ out, int M) {

    __shared__ unsigned short A_sh[128 * 128];
    __shared__ unsigned short B_sh[128 * 128];
    char* Ab = (char*)A_sh;
    char* Bb = (char*)B_sh;
    const char* Wb = (const char*)Wbf;

    const int tid = threadIdx.x;
    const int n0 = blockIdx.x * 128;
    const int wid = tid >> 6;
    const int lane = tid & 63;
    const int wr = wid >> 1;
    const int wc = wid & 1;
    const int fr = lane & 15;
    const int fq = lane >> 4;

    f32x4 acc[4][4];
#pragma unroll
    for (int m = 0; m < 4; m++)
#pragma unroll
        for (int n = 0; n < 4; n++) acc[m][n] = (f32x4)(0.0f);

#pragma unroll
    for (int p = 0; p < 2; p++) {
        const char* Asrc = (const char*)(p == 0 ? Xh : Xf);
#pragma unroll
        for (int it = 0; it < 8; it++) {
            int idx = it * 256 + tid;
            int row = idx >> 4;
            int ch = idx & 15;
            int off = ((row << 8) + (ch << 4)) ^ ((row & 7) << 4);
            int nrow = n0 + row;
            uint4 va = make_uint4(0u, 0u, 0u, 0u);
            if (nrow < M)
                va = *reinterpret_cast<const uint4*>(Asrc + (size_t)nrow * 256 + ch * 16);
            *reinterpret_cast<uint4*>(Ab + off) = va;
            uint4 vb = *reinterpret_cast<const uint4*>(Wb + (size_t)row * 512 + p * 256 + ch * 16);
            *reinterpret_cast<uint4*>(Bb + off) = vb;
        }
        __syncthreads();

#pragma unroll
        for (int ks = 0; ks < 4; ks++) {
            const int k = ks * 32 + fq * 8;
            bf16x8 af[4], bf_[4];
#pragma unroll
            for (int m = 0; m < 4; m++) {
                int row = wr * 64 + m * 16 + fr;
                int off = ((row << 8) + (k << 1)) ^ ((row & 7) << 4);
                af[m] = *reinterpret_cast<const bf16x8*>(Ab + off);
            }
#pragma unroll
            for (int n = 0; n < 4; n++) {
                int col = wc * 64 + n * 16 + fr;
                int off = ((col << 8) + (k << 1)) ^ ((col & 7) << 4);
                bf_[n] = *reinterpret_cast<const bf16x8*>(Bb + off);
            }
#pragma unroll
            for (int m = 0; m < 4; m++)
#pragma unroll
                for (int n = 0; n < 4; n++)
                    acc[m][n] = __builtin_amdgcn_mfma_f32_16x16x32_bf16(af[m], bf_[n], acc[m][n], 0, 0, 0);
        }
        if (p == 0) __syncthreads();
    }

    float bv[4];
#pragma unroll
    for (int n = 0; n < 4; n++) bv[n] = bias[wc * 64 + n * 16 + fr];

#pragma unroll
    for (int m = 0; m < 4; m++) {
        int rbase = n0 + wr * 64 + m * 16 + fq * 4;
#pragma unroll
        for (int n = 0; n < 4; n++) {
            int col = wc * 64 + n * 16 + fr;
#pragma unroll
            for (int j = 0; j < 4; j++) {
                int r = rbase + j;
                if (r < M) out[(size_t)r * 128 + col] = acc[m][n][j] + bv[n];
            }
        }
    }
}

extern "C" void kernel_launch(void* const* d_in, const int* in_sizes, int n_in,
                              void* d_out, int out_size, void* d_ws, size_t ws_size,
                              hipStream_t stream) {
    const float* feature = (const float*)d_in[0];
    const int*   src     = (const int*)d_in[1];
    const int*   dst     = (const int*)d_in[2];
    const float* W       = (const float*)d_in[3];
    const float* bias    = (const float*)d_in[4];
    float* out = (float*)d_out;

    const int M  = in_sizes[0] / D_IN;   // 50000
    const int nE = in_sizes[1];          // 800000

    char* w = (char*)d_ws;
    unsigned short* Xh  = (unsigned short*)w;              // M*128 bf16 (agg out)
    unsigned short* Xf  = Xh + (size_t)M * 128;            // M*128 bf16 (feature)
    unsigned char*  Xq  = (unsigned char*)(Xf + (size_t)M * 128);  // M*128 fp8
    unsigned short* Wbf = (unsigned short*)(Xq + (size_t)M * 128); // 128*256 bf16
    int* bcursor = (int*)(Wbf + 128 * 256);                // NB
    unsigned* rstart = (unsigned*)(bcursor + NB);          // M
    unsigned* bedges = (unsigned*)(rstart + M);            // NB*CAP

    size_t fixed = (size_t)((char*)bedges - w);
    long avail = (long)ws_size - (long)fixed;
    int CAP = (int)(avail / (NB * 4));
    if (CAP > CAPMAX) CAP = CAPMAX;
    if (CAP < 1) CAP = 1;

    hipMemsetAsync(bcursor, 0, NB * sizeof(int), stream);

    const int blocks_f = (M * D_IN) / (256 * 8);           // 3125
    convert_kernel<<<blocks_f + 16, 256, 0, stream>>>(feature, W, Xf, Xq, Wbf, M, blocks_f);
    {
        int blocks = (nE + EPB - 1) / EPB;                 // 196
        coarse_scatter_kernel<<<blocks, 256, 0, stream>>>(src, dst, bcursor, bedges, CAP, nE);
    }
    {
        int blocks = (M + 127) / 128;                      // 391
        fine_sort_kernel<<<blocks, 256, 0, stream>>>(bedges, bcursor, rstart, CAP, M);
    }
    {
        size_t totalT = (size_t)M * 64;
        int blocks = (int)((totalT + 255) / 256);          // 12500
        node_agg_kernel<<<blocks, 256, 0, stream>>>(Xq, Xh, bedges, rstart, M);
    }
    {
        int blocks = (M + 127) / 128;                      // 391
        gcn_gemm_kernel<<<blocks, 256, 0, stream>>>(Xh, Xf, Wbf, bias, out, M);
    }
}

// Round 14
// 80.861 us; speedup vs baseline: 1.0792x; 1.0792x over previous
//
#include <hip/hip_runtime.h>
#include <hip/hip_bf16.h>

// GCN layer. N=50000, E=800000, D=128, D_OUT=128, f32 in/out.
// out = concat(mean_agg(feature,src,dst), feature) @ W.T + b
//
// R14: R13's index-preload node_agg with the __shfl divergence bug fixed:
// chunk loop bound is wave-uniform, __shfl always executes with all 64 lanes
// active (clamped src index), only the gather+accumulate is predicated.
// (R13: per-quarter trip counts diverged -> shfl pulled from inactive lanes.)

#define D_IN 128
#define NB 391          // buckets = ceil(50000/128)
#define BSHIFT 7
#define EPB 4096        // edges per coarse block
#define CAPMAX 2680     // NB*CAP < 2^20 (packed rstart)

typedef __attribute__((ext_vector_type(8))) short bf16x8;
typedef __attribute__((ext_vector_type(4))) float f32x4;

static __device__ inline unsigned short f2bf(float x) {
    union { float f; unsigned u; } c; c.f = x;
    unsigned u = c.u;
    unsigned r = u + 0x7FFFu + ((u >> 16) & 1u);
    return (unsigned short)(r >> 16);
}
static __device__ inline float bflo(unsigned u) { return __uint_as_float(u << 16); }
static __device__ inline float bfhi(unsigned u) { return __uint_as_float(u & 0xFFFF0000u); }

// ---- dispatch 1: convert feature->Xf bf16, W->Wbf; tail block inits bcursor ----
__global__ __launch_bounds__(256) void convert_kernel(const float* __restrict__ feat,
                                                      const float* __restrict__ W,
                                                      unsigned short* __restrict__ Xf,
                                                      unsigned short* __restrict__ Wbf,
                                                      int* __restrict__ bcursor,
                                                      int M, int blocks_f) {
    int b = blockIdx.x;
    if (b < blocks_f) {
        size_t idx = ((size_t)b * 256 + threadIdx.x) * 8;
        if (idx >= (size_t)M * 128) return;
        float4 v0 = *reinterpret_cast<const float4*>(feat + idx);
        float4 v1 = *reinterpret_cast<const float4*>(feat + idx + 4);
        uint4 p;
        p.x = (unsigned)f2bf(v0.x) | ((unsigned)f2bf(v0.y) << 16);
        p.y = (unsigned)f2bf(v0.z) | ((unsigned)f2bf(v0.w) << 16);
        p.z = (unsigned)f2bf(v1.x) | ((unsigned)f2bf(v1.y) << 16);
        p.w = (unsigned)f2bf(v1.z) | ((unsigned)f2bf(v1.w) << 16);
        *reinterpret_cast<uint4*>(Xf + idx) = p;
    } else if (b < blocks_f + 16) {
        int idx = ((b - blocks_f) * 256 + (int)threadIdx.x) * 8;
        if (idx >= 128 * 256) return;
        float4 v0 = *reinterpret_cast<const float4*>(W + idx);
        float4 v1 = *reinterpret_cast<const float4*>(W + idx + 4);
        uint4 p;
        p.x = (unsigned)f2bf(v0.x) | ((unsigned)f2bf(v0.y) << 16);
        p.y = (unsigned)f2bf(v0.z) | ((unsigned)f2bf(v0.w) << 16);
        p.z = (unsigned)f2bf(v1.x) | ((unsigned)f2bf(v1.y) << 16);
        p.w = (unsigned)f2bf(v1.z) | ((unsigned)f2bf(v1.w) << 16);
        *reinterpret_cast<uint4*>(Wbf + idx) = p;
    } else {
        for (int i = threadIdx.x; i < NB; i += 256) bcursor[i] = 0;
    }
}

// ---- dispatch 2: coarse bucket scatter (LDS counting sort by dst>>7) ----
__global__ __launch_bounds__(256) void coarse_scatter_kernel(
    const int* __restrict__ src, const int* __restrict__ dst,
    int* __restrict__ bcursor, unsigned* __restrict__ bedges,
    int CAP, int nE) {
    __shared__ int hist[NB];
    __shared__ int lofs[NB + 1];
    __shared__ int rnk[NB];
    __shared__ int gbase[NB];
    __shared__ int wsum[4];
    __shared__ unsigned staged[EPB];

    const int tid = threadIdx.x;
    const int e0 = blockIdx.x * EPB;
    for (int i = tid; i < NB; i += 256) { hist[i] = 0; rnk[i] = 0; }
    __syncthreads();

    for (int k = 0; k < EPB; k += 256) {
        int e = e0 + k + tid;
        if (e < nE) atomicAdd(&hist[dst[e] >> BSHIFT], 1);
    }
    __syncthreads();

    {   // exclusive scan of hist -> lofs (2 elems/thread)
        int a = (2 * tid < NB) ? hist[2 * tid] : 0;
        int c = (2 * tid + 1 < NB) ? hist[2 * tid + 1] : 0;
        int ps = a + c;
        int x = ps;
        int lane = tid & 63, wv = tid >> 6;
#pragma unroll
        for (int off = 1; off < 64; off <<= 1) {
            int y = __shfl_up(x, off);
            if (lane >= off) x += y;
        }
        if (lane == 63) wsum[wv] = x;
        __syncthreads();
        if (tid == 0) {
            int s = 0;
#pragma unroll
            for (int w = 0; w < 4; w++) { int v = wsum[w]; wsum[w] = s; s += v; }
        }
        __syncthreads();
        int excl = x - ps + wsum[wv];
        if (2 * tid < NB + 1) lofs[2 * tid] = excl;
        if (2 * tid + 1 < NB + 1) lofs[2 * tid + 1] = excl + a;
    }
    __syncthreads();

    for (int i = tid; i < NB; i += 256)
        if (hist[i] > 0) gbase[i] = i * CAP + atomicAdd(&bcursor[i], hist[i]);

    for (int k = 0; k < EPB; k += 256) {
        int e = e0 + k + tid;
        if (e < nE) {
            int d = dst[e];
            int bk = d >> BSHIFT;
            unsigned ed = ((unsigned)d << 16) | (unsigned)src[e];
            int r = atomicAdd(&rnk[bk], 1);
            staged[lofs[bk] + r] = ed;
        }
    }
    __syncthreads();

    int total = lofs[NB];
    for (int i = tid; i < total; i += 256) {
        unsigned ed = staged[i];
        int bk = (int)(ed >> 23);
        int addr = gbase[bk] + (i - lofs[bk]);
        if (addr < (bk + 1) * CAP) bedges[addr] = ed;   // overflow guard
    }
}

// ---- dispatch 3: per-bucket fine counting sort by dst&127; packed rstart ----
__global__ __launch_bounds__(256) void fine_sort_kernel(
    unsigned* __restrict__ bedges, const int* __restrict__ bcursor,
    unsigned* __restrict__ rstart, int CAP, int N) {
    __shared__ int h[128];
    __shared__ int lofs[129];
    __shared__ int rnk[128];
    __shared__ unsigned staged[CAPMAX + 8];

    const int b = blockIdx.x;
    const int S = b * CAP;
    const int tid = threadIdx.x;
    int cnt = min(bcursor[b], CAP);

    if (tid < 128) { h[tid] = 0; rnk[tid] = 0; }
    __syncthreads();
    for (int i = tid; i < cnt; i += 256) {
        unsigned ed = bedges[S + i];
        atomicAdd(&h[(ed >> 16) & 127], 1);
    }
    __syncthreads();
    if (tid < 64) {
        int a = h[2 * tid], c = h[2 * tid + 1];
        int ps = a + c;
        int x = ps;
#pragma unroll
        for (int off = 1; off < 64; off <<= 1) {
            int y = __shfl_up(x, off);
            if (tid >= off) x += y;
        }
        int excl = x - ps;
        lofs[2 * tid] = excl;
        lofs[2 * tid + 1] = excl + a;
        if (tid == 63) lofs[128] = x;
    }
    __syncthreads();
    for (int i = tid; i < cnt; i += 256) {
        unsigned ed = bedges[S + i];
        int ld = (ed >> 16) & 127;
        int r = atomicAdd(&rnk[ld], 1);
        staged[lofs[ld] + r] = ed;
    }
    __syncthreads();
    for (int i = tid; i < cnt; i += 256) bedges[S + i] = staged[i];
    if (tid < 128) {
        int node = b * 128 + tid;
        if (node < N)
            rstart[node] = (((unsigned)(S + lofs[tid])) << 12) | (unsigned)h[tid];
    }
}

// ---- dispatch 4: per-node mean; index preload + UNIFORM shfl broadcast ----
__global__ __launch_bounds__(256) void node_agg_kernel(const unsigned short* __restrict__ Xf,
                                                       unsigned short* __restrict__ Xh,
                                                       const unsigned* __restrict__ bedges,
                                                       const unsigned* __restrict__ rstart, int N) {
    int wid = (int)((blockIdx.x * (size_t)blockDim.x + threadIdx.x) >> 6);
    if (wid >= N) return;
    const int lane = threadIdx.x & 63;
    const int q = lane >> 4;          // quarter 0..3
    const int sl = lane & 15;         // 16B chunk within 256B row
    const unsigned pk = rstart[wid];
    const int s = (int)(pk >> 12);
    const int cnt = (int)(pk & 4095u);
    const char* Xb = (const char*)Xf;
    const size_t coff = (size_t)sl * 16;

    float a0=0.f,a1=0.f,a2=0.f,a3=0.f,a4=0.f,a5=0.f,a6=0.f,a7=0.f;

    int base = s, rem = cnt;
    while (rem > 0) {                 // rem is wave-uniform
        const int take = min(rem, 64);
        int idx_l = 0;
        if (lane < take) idx_l = (int)(bedges[base + lane] & 0xFFFFu);
        // uniform loop bound; shfl always runs with all 64 lanes active
        for (int tb = 0; tb < take; tb += 8) {
            int i0 = tb + q;
            int i1 = tb + q + 4;
            int u0 = __shfl(idx_l, (i0 < take) ? i0 : 0);
            int u1 = __shfl(idx_l, (i1 < take) ? i1 : 0);
            if (i0 < take) {
                uint4 va = *reinterpret_cast<const uint4*>(Xb + (size_t)u0 * 256 + coff);
                a0 += bflo(va.x); a1 += bfhi(va.x);
                a2 += bflo(va.y); a3 += bfhi(va.y);
                a4 += bflo(va.z); a5 += bfhi(va.z);
                a6 += bflo(va.w); a7 += bfhi(va.w);
            }
            if (i1 < take) {
                uint4 vb = *reinterpret_cast<const uint4*>(Xb + (size_t)u1 * 256 + coff);
                a0 += bflo(vb.x); a1 += bfhi(vb.x);
                a2 += bflo(vb.y); a3 += bfhi(vb.y);
                a4 += bflo(vb.z); a5 += bfhi(vb.z);
                a6 += bflo(vb.w); a7 += bfhi(vb.w);
            }
        }
        base += take; rem -= take;
    }

    a0 += __shfl_down(a0, 32); a1 += __shfl_down(a1, 32);
    a2 += __shfl_down(a2, 32); a3 += __shfl_down(a3, 32);
    a4 += __shfl_down(a4, 32); a5 += __shfl_down(a5, 32);
    a6 += __shfl_down(a6, 32); a7 += __shfl_down(a7, 32);
    a0 += __shfl_down(a0, 16); a1 += __shfl_down(a1, 16);
    a2 += __shfl_down(a2, 16); a3 += __shfl_down(a3, 16);
    a4 += __shfl_down(a4, 16); a5 += __shfl_down(a5, 16);
    a6 += __shfl_down(a6, 16); a7 += __shfl_down(a7, 16);
    if (lane < 16) {
        float r = 1.0f / fmaxf((float)cnt, 1.0f);
        uint4 p;
        p.x = (unsigned)f2bf(a0 * r) | ((unsigned)f2bf(a1 * r) << 16);
        p.y = (unsigned)f2bf(a2 * r) | ((unsigned)f2bf(a3 * r) << 16);
        p.z = (unsigned)f2bf(a4 * r) | ((unsigned)f2bf(a5 * r) << 16);
        p.w = (unsigned)f2bf(a6 * r) | ((unsigned)f2bf(a7 * r) << 16);
        *reinterpret_cast<uint4*>((char*)Xh + (size_t)wid * 256 + sl * 16) = p;
    }
}

// ---- dispatch 5: out[M,128] = [Xh|Xf]bf16 @ Wbf[128,256]^T + b via MFMA ----
__global__ __launch_bounds__(256) void gcn_gemm_kernel(
    const unsigned short* __restrict__ Xh, const unsigned short* __restrict__ Xf,
    const unsigned short* __restrict__ Wbf,
    const float* __restrict__ bias, float* __restrict__ out, int M) {

    __shared__ unsigned short A_sh[128 * 128];
    __shared__ unsigned short B_sh[128 * 128];
    char* Ab = (char*)A_sh;
    char* Bb = (char*)B_sh;
    const char* Wb = (const char*)Wbf;

    const int tid = threadIdx.x;
    const int n0 = blockIdx.x * 128;
    const int wid = tid >> 6;
    const int lane = tid & 63;
    const int wr = wid >> 1;
    const int wc = wid & 1;
    const int fr = lane & 15;
    const int fq = lane >> 4;

    f32x4 acc[4][4];
#pragma unroll
    for (int m = 0; m < 4; m++)
#pragma unroll
        for (int n = 0; n < 4; n++) acc[m][n] = (f32x4)(0.0f);

#pragma unroll
    for (int p = 0; p < 2; p++) {
        const char* Asrc = (const char*)(p == 0 ? Xh : Xf);
#pragma unroll
        for (int it = 0; it < 8; it++) {
            int idx = it * 256 + tid;
            int row = idx >> 4;
            int ch = idx & 15;
            int off = ((row << 8) + (ch << 4)) ^ ((row & 7) << 4);
            int nrow = n0 + row;
            uint4 va = make_uint4(0u, 0u, 0u, 0u);
            if (nrow < M)
                va = *reinterpret_cast<const uint4*>(Asrc + (size_t)nrow * 256 + ch * 16);
            *reinterpret_cast<uint4*>(Ab + off) = va;
            uint4 vb = *reinterpret_cast<const uint4*>(Wb + (size_t)row * 512 + p * 256 + ch * 16);
            *reinterpret_cast<uint4*>(Bb + off) = vb;
        }
        __syncthreads();

#pragma unroll
        for (int ks = 0; ks < 4; ks++) {
            const int k = ks * 32 + fq * 8;
            bf16x8 af[4], bf_[4];
#pragma unroll
            for (int m = 0; m < 4; m++) {
                int row = wr * 64 + m * 16 + fr;
                int off = ((row << 8) + (k << 1)) ^ ((row & 7) << 4);
                af[m] = *reinterpret_cast<const bf16x8*>(Ab + off);
            }
#pragma unroll
            for (int n = 0; n < 4; n++) {
                int col = wc * 64 + n * 16 + fr;
                int off = ((col << 8) + (k << 1)) ^ ((col & 7) << 4);
                bf_[n] = *reinterpret_cast<const bf16x8*>(Bb + off);
            }
#pragma unroll
            for (int m = 0; m < 4; m++)
#pragma unroll
                for (int n = 0; n < 4; n++)
                    acc[m][n] = __builtin_amdgcn_mfma_f32_16x16x32_bf16(af[m], bf_[n], acc[m][n], 0, 0, 0);
        }
        if (p == 0) __syncthreads();
    }

    float bv[4];
#pragma unroll
    for (int n = 0; n < 4; n++) bv[n] = bias[wc * 64 + n * 16 + fr];

#pragma unroll
    for (int m = 0; m < 4; m++) {
        int rbase = n0 + wr * 64 + m * 16 + fq * 4;
#pragma unroll
        for (int n = 0; n < 4; n++) {
            int col = wc * 64 + n * 16 + fr;
#pragma unroll
            for (int j = 0; j < 4; j++) {
                int r = rbase + j;
                if (r < M) out[(size_t)r * 128 + col] = acc[m][n][j] + bv[n];
            }
        }
    }
}

extern "C" void kernel_launch(void* const* d_in, const int* in_sizes, int n_in,
                              void* d_out, int out_size, void* d_ws, size_t ws_size,
                              hipStream_t stream) {
    const float* feature = (const float*)d_in[0];
    const int*   src     = (const int*)d_in[1];
    const int*   dst     = (const int*)d_in[2];
    const float* W       = (const float*)d_in[3];
    const float* bias    = (const float*)d_in[4];
    float* out = (float*)d_out;

    const int M  = in_sizes[0] / D_IN;   // 50000
    const int nE = in_sizes[1];          // 800000

    char* w = (char*)d_ws;
    unsigned short* Xh  = (unsigned short*)w;              // M*128 bf16 (agg out)
    unsigned short* Xf  = Xh + (size_t)M * 128;            // M*128 bf16 (feature)
    unsigned short* Wbf = Xf + (size_t)M * 128;            // 128*256 bf16
    int* bcursor = (int*)(Wbf + 128 * 256);                // NB
    unsigned* rstart = (unsigned*)(bcursor + NB);          // M
    unsigned* bedges = (unsigned*)(rstart + M);            // NB*CAP

    size_t fixed = (size_t)((char*)bedges - w);
    long avail = (long)ws_size - (long)fixed;
    int CAP = (int)(avail / (NB * 4));
    if (CAP > CAPMAX) CAP = CAPMAX;
    if (CAP < 1) CAP = 1;

    const int blocks_f = (M * D_IN) / (256 * 8);           // 3125
    convert_kernel<<<blocks_f + 17, 256, 0, stream>>>(feature, W, Xf, Wbf, bcursor, M, blocks_f);
    {
        int blocks = (nE + EPB - 1) / EPB;                 // 196
        coarse_scatter_kernel<<<blocks, 256, 0, stream>>>(src, dst, bcursor, bedges, CAP, nE);
    }
    {
        int blocks = (M + 127) / 128;                      // 391
        fine_sort_kernel<<<blocks, 256, 0, stream>>>(bedges, bcursor, rstart, CAP, M);
    }
    {
        size_t totalT = (size_t)M * 64;
        int blocks = (int)((totalT + 255) / 256);          // 12500
        node_agg_kernel<<<blocks, 256, 0, stream>>>(Xf, Xh, bedges, rstart, M);
    }
    {
        int blocks = (M + 127) / 128;                      // 391
        gcn_gemm_kernel<<<blocks, 256, 0, stream>>>(Xh, Xf, Wbf, bias, out, M);
    }
}